// Round 1
// baseline (16261.395 us; speedup 1.0000x reference)
//
#include <hip/hip_runtime.h>
#include <cstdint>
#include <cstddef>

// ---------------------------------------------------------------------------
// GAT x3 (exact JAX-threefry dropout, PARTITIONABLE mode) + SAGPool x7.
// Round 5:
//  * gat_out_k / pool_agg_k: software-pipelined edge loop (index chain staged
//    3 ahead, 800B row gather staged 2 ahead). Accumulation order is UNCHANGED
//    (CSR edge order, self-loop last) -> bitwise-identical FP results.
//  * rank_k (O(n^2)) replaced by bucketed exact rank (O(n)): 2048-bin histogram
//    over order-preserving score encoding + within-bucket 64-bit key count.
//    key = (enc<<32)|~idx reproduces (s_j>s_i)||(s_j==s_i && j<i) exactly
//    (-0 canonicalized to +0 before encoding).
// All segment ops remain deterministic + np-association-matched (CSR serial).
// Workspace: ~95.5 MB (unchanged; selection reuses GAT-phase scratch).
// ---------------------------------------------------------------------------

__host__ __device__ inline void tf_round(uint32_t &x0, uint32_t &x1, int r) {
  x0 += x1;
  x1 = (x1 << r) | (x1 >> (32 - r));
  x1 ^= x0;
}

// Exact jax threefry2x32 (Random123 KAT: key(0,0),ctr(0,0) -> 6b200159 99ba4efe)
__host__ __device__ inline void threefry2x32(uint32_t k0, uint32_t k1,
                                             uint32_t &x0, uint32_t &x1) {
  uint32_t ks2 = k0 ^ k1 ^ 0x1BD11BDAu;
  x0 += k0; x1 += k1;
  tf_round(x0, x1, 13); tf_round(x0, x1, 15); tf_round(x0, x1, 26); tf_round(x0, x1, 6);
  x0 += k1; x1 += ks2 + 1u;
  tf_round(x0, x1, 17); tf_round(x0, x1, 29); tf_round(x0, x1, 16); tf_round(x0, x1, 24);
  x0 += ks2; x1 += k0 + 2u;
  tf_round(x0, x1, 13); tf_round(x0, x1, 15); tf_round(x0, x1, 26); tf_round(x0, x1, 6);
  x0 += k0; x1 += k1 + 3u;
  tf_round(x0, x1, 17); tf_round(x0, x1, 29); tf_round(x0, x1, 16); tf_round(x0, x1, 24);
  x0 += k1; x1 += ks2 + 4u;
  tf_round(x0, x1, 13); tf_round(x0, x1, 15); tf_round(x0, x1, 26); tf_round(x0, x1, 6);
  x0 += ks2; x1 += k0 + 5u;
}

// ---------------- GEMM: C[M x 200] = A[M x K] @ B[K x 200], fp32 -------------
__global__ __launch_bounds__(256) void gemm200_k(
    const float* __restrict__ A, const float* __restrict__ B,
    float* __restrict__ C, int M, int K) {
  __shared__ __align__(16) float As[128 * 8];
  __shared__ __align__(16) float Bs[8][208];
  int tid = threadIdx.x;
  int m0 = blockIdx.x * 128;
  int r = tid >> 2;
  int colBase = (tid & 3) * 52;
  float acc0[52], acc1[52];
#pragma unroll
  for (int q = 0; q < 52; q++) { acc0[q] = 0.f; acc1[q] = 0.f; }

  for (int k0 = 0; k0 < K; k0 += 8) {
    {
      int row = tid >> 1;
      int c = (tid & 1) * 4;
      int gm = m0 + row;
      float4 v = make_float4(0.f, 0.f, 0.f, 0.f);
      if (gm < M) v = *(const float4*)(A + (size_t)gm * K + (k0 + c));
      *(float4*)(&As[row * 8 + c]) = v;
    }
    for (int t = tid; t < 400; t += 256) {
      int kk = t / 50;
      int c = (t - kk * 50) * 4;
      *(float4*)(&Bs[kk][c]) = *(const float4*)(B + (size_t)(k0 + kk) * 200 + c);
    }
    __syncthreads();
#pragma unroll
    for (int kk = 0; kk < 8; kk++) {
      float a0 = As[r * 8 + kk];
      float a1 = As[(r + 64) * 8 + kk];
#pragma unroll
      for (int q = 0; q < 13; q++) {
        float4 b = *(const float4*)(&Bs[kk][colBase + 4 * q]);
        acc0[4 * q + 0] += a0 * b.x; acc0[4 * q + 1] += a0 * b.y;
        acc0[4 * q + 2] += a0 * b.z; acc0[4 * q + 3] += a0 * b.w;
        acc1[4 * q + 0] += a1 * b.x; acc1[4 * q + 1] += a1 * b.y;
        acc1[4 * q + 2] += a1 * b.z; acc1[4 * q + 3] += a1 * b.w;
      }
    }
    __syncthreads();
  }
  int gm0 = m0 + r, gm1 = m0 + r + 64;
#pragma unroll
  for (int q = 0; q < 52; q++) {
    int col = colBase + q;
    if (col < 200) {
      if (gm0 < M) C[(size_t)gm0 * 200 + col] = acc0[q];
      if (gm1 < M) C[(size_t)gm1 * 200 + col] = acc1[q];
    }
  }
}

// ---------------- dual dot: o1[i]=H[i]·v1, o2[i]=H[i]·v2 (one wave/node) -----
__global__ __launch_bounds__(256) void dual_dot_k(
    const float* __restrict__ H, const float* __restrict__ v1,
    const float* __restrict__ v2, float* __restrict__ o1,
    float* __restrict__ o2, int n) {
  int wave = blockIdx.x * 4 + (threadIdx.x >> 6);
  int lane = threadIdx.x & 63;
  if (wave >= n) return;
  const float* row = H + (size_t)wave * 200;
  float s1 = 0.f, s2 = 0.f;
  for (int d = lane; d < 200; d += 64) {
    float h = row[d];
    s1 += h * v1[d];
    s2 += h * v2[d];
  }
  for (int off = 32; off; off >>= 1) {
    s1 += __shfl_down(s1, off);
    s2 += __shfl_down(s2, off);
  }
  if (lane == 0) { o1[wave] = s1; o2[wave] = s2; }
}

// ---------------- CSR build (dst-sorted, stable by edge index) ---------------
__global__ __launch_bounds__(256) void indeg_k(const int* __restrict__ dst,
                                               int* __restrict__ cnt, int E) {
  int e = blockIdx.x * 256 + threadIdx.x;
  if (e < E) atomicAdd(&cnt[dst[e]], 1);
}

// single block, 256 threads: exclusive scan cnt[0..N) -> rowptr[0..N]
__global__ __launch_bounds__(256) void scan_k(const int* __restrict__ cnt,
                                              int* __restrict__ rowptr, int N) {
  __shared__ int psum[256];
  int t = threadIdx.x;
  int CH = (N + 255) / 256;
  int beg = t * CH, end = min(beg + CH, N);
  if (beg > N) { beg = N; }
  int s = 0;
  for (int i = beg; i < end; i++) s += cnt[i];
  psum[t] = s;
  __syncthreads();
  if (t == 0) {
    int run = 0;
    for (int i = 0; i < 256; i++) { int v = psum[i]; psum[i] = run; run += v; }
  }
  __syncthreads();
  int run = psum[t];
  for (int i = beg; i < end; i++) { rowptr[i] = run; run += cnt[i]; }
  if (end == N && beg <= N) rowptr[N] = run;
}

__global__ __launch_bounds__(256) void cpyint_k(const int* __restrict__ a,
                                                int* __restrict__ b, int n) {
  int i = blockIdx.x * 256 + threadIdx.x;
  if (i < n) b[i] = a[i];
}

__global__ __launch_bounds__(256) void place_k(const int* __restrict__ dst,
                                               int* __restrict__ curs,
                                               int* __restrict__ csr, int E) {
  int e = blockIdx.x * 256 + threadIdx.x;
  if (e >= E) return;
  int pos = atomicAdd(&curs[dst[e]], 1);
  csr[pos] = e;
}

__global__ __launch_bounds__(256) void sortrow_k(const int* __restrict__ rowptr,
                                                 int* __restrict__ csr, int N) {
  int d = blockIdx.x * 256 + threadIdx.x;
  if (d >= N) return;
  int b = rowptr[d], e2 = rowptr[d + 1];
  for (int i = b + 1; i < e2; i++) {
    int v = csr[i];
    int j = i - 1;
    while (j >= b && csr[j] > v) { csr[j + 1] = csr[j]; j--; }
    csr[j + 1] = v;
  }
}

// ---------------- GAT edge softmax (deterministic, np order) -----------------
__device__ inline float dec_ord(unsigned enc) {
  unsigned b = (enc & 0x80000000u) ? (enc ^ 0x80000000u) : ~enc;
  return __uint_as_float(b);
}

__global__ __launch_bounds__(256) void edge_max_k(
    const int* __restrict__ src, const int* __restrict__ dst,
    const float* __restrict__ as_, const float* __restrict__ ad_,
    unsigned* __restrict__ menc, int E, int N) {
  int j = blockIdx.x * 256 + threadIdx.x;
  if (j >= E + N) return;
  int s, d;
  if (j < E) { s = src[j]; d = dst[j]; } else { s = j - E; d = s; }
  float v = as_[s] + ad_[d];
  float ev = (v >= 0.f) ? v : 0.2f * v;  // leaky_relu 0.2
  unsigned b = __float_as_uint(ev);
  unsigned enc = (b & 0x80000000u) ? ~b : (b | 0x80000000u);
  atomicMax(&menc[d], enc);
}

__global__ __launch_bounds__(256) void ee_k(
    const int* __restrict__ src, const int* __restrict__ dst,
    const float* __restrict__ as_, const float* __restrict__ ad_,
    const unsigned* __restrict__ menc, float* __restrict__ ee, int E, int N) {
  int j = blockIdx.x * 256 + threadIdx.x;
  if (j >= E + N) return;
  int s, d;
  if (j < E) { s = src[j]; d = dst[j]; } else { s = j - E; d = s; }
  float v = as_[s] + ad_[d];
  float ev = (v >= 0.f) ? v : 0.2f * v;
  ee[j] = expf(ev - dec_ord(menc[d]));
}

// denom per node: serial sum in edge-index order, self-loop (index E+d) LAST.
__global__ __launch_bounds__(256) void den_k(const int* __restrict__ rowptr,
                                             const int* __restrict__ csr,
                                             const float* __restrict__ ee,
                                             float* __restrict__ den, int E, int N) {
  int d = blockIdx.x * 256 + threadIdx.x;
  if (d >= N) return;
  float s = 0.f;
  int b = rowptr[d], e2 = rowptr[d + 1];
  for (int i = b; i < e2; i++) s = __fadd_rn(s, ee[csr[i]]);
  s = __fadd_rn(s, ee[E + d]);
  den[d] = s;
}

__global__ __launch_bounds__(256) void alpha_k(const int* __restrict__ dst,
                                               const float* __restrict__ den,
                                               float* __restrict__ ee, int E, int N) {
  int j = blockIdx.x * 256 + threadIdx.x;
  if (j >= E + N) return;
  int d = (j < E) ? dst[j] : (j - E);
  ee[j] = ee[j] / den[d];
}

// GAT out: wave per node, serial over edges (edge-index order, self last).
// Software-pipelined: index chain (csr->src/alpha) staged 3 slots ahead,
// 800B HW-row gather staged 2 slots ahead. Tail slots carry w=0 and, since
// acc starts at +0.0 and 0*finite = +/-0, the extra adds are exact no-ops:
// accumulation order/values are bitwise identical to the serial version.
__global__ __launch_bounds__(256) void gat_out_k(
    const int* __restrict__ rowptr, const int* __restrict__ csr,
    const int* __restrict__ src, const float* __restrict__ alpha,
    const float* __restrict__ HW, float* __restrict__ OUT, int E, int N) {
  int node = blockIdx.x * 4 + (threadIdx.x >> 6);
  int lane = threadIdx.x & 63;
  if (node >= N || lane >= 50) return;
  int b = rowptr[node];
  int deg = rowptr[node + 1] - b;
  int cnt = deg + 1;  // edges then self-loop (last)

  auto fetchS = [&](int t, int &s, float &w) {
    if (t < deg) {
      int e = csr[b + t];
      s = src[e];
      w = alpha[e];
    } else if (t == deg) {
      s = node;
      w = alpha[E + node];
    } else {
      s = node;  // valid dummy row
      w = 0.f;
    }
  };

  int s0, s1, s2;
  float w0, w1, w2;
  fetchS(0, s0, w0);
  fetchS(1, s1, w1);
  fetchS(2, s2, w2);
  float4 h0 = *(const float4*)(HW + (size_t)s0 * 200 + 4 * lane);
  float4 h1 = *(const float4*)(HW + (size_t)s1 * 200 + 4 * lane);
  float4 acc = make_float4(0.f, 0.f, 0.f, 0.f);
  for (int t = 0; t < cnt; t++) {
    int s3;
    float w3;
    fetchS(t + 3, s3, w3);
    float4 h2 = *(const float4*)(HW + (size_t)s2 * 200 + 4 * lane);
    acc.x = __fadd_rn(acc.x, __fmul_rn(w0, h0.x));
    acc.y = __fadd_rn(acc.y, __fmul_rn(w0, h0.y));
    acc.z = __fadd_rn(acc.z, __fmul_rn(w0, h0.z));
    acc.w = __fadd_rn(acc.w, __fmul_rn(w0, h0.w));
    h0 = h1; h1 = h2;
    w0 = w1; w1 = w2; w2 = w3;
    s2 = s3;
  }
  *(float4*)(OUT + (size_t)node * 200 + 4 * lane) = acc;
}

// -------- epilogue: bias + relu + JAX partitionable-threefry dropout ---------
__global__ __launch_bounds__(256) void epi_k(float* __restrict__ H,
                                             const float* __restrict__ bias,
                                             uint32_t k0, uint32_t k1, int total) {
  int t = blockIdx.x * 256 + threadIdx.x;
  if (t >= total) return;
  uint32_t x0 = 0u, x1 = (uint32_t)t;  // hi32(i)=0, lo32(i)=i  (i < 2^32)
  threefry2x32(k0, k1, x0, x1);
  uint32_t bits = x0 ^ x1;
  float u = __uint_as_float((bits >> 9) | 0x3f800000u) - 1.0f;
  int col = t % 200;
  float v = H[t] + bias[col];
  v = fmaxf(v, 0.f);
  H[t] = (u < 0.8f) ? (v / 0.8f) : 0.f;
}

// ---------------- pooling kernels -------------------------------------------
__global__ __launch_bounds__(256) void einit_k(
    const int* __restrict__ src, const int* __restrict__ dst,
    int* __restrict__ cs, int* __restrict__ cd, int* __restrict__ orig,
    int E, int N) {
  int e = blockIdx.x * 256 + threadIdx.x;
  if (e < E) { cs[e] = src[e]; cd[e] = dst[e]; }
  if (e < N) orig[e] = e;
}

// agg[d'] = sum over valid edges (orig CSR row of orig[d'], ascending e) of h[csrc[e]]
// Same software pipeline as gat_out_k; invalid edges contribute w=0 (exact no-op
// since acc starts +0.0, so association matches the skip-based serial version).
__global__ __launch_bounds__(256) void pool_agg_k(
    const int* __restrict__ rowptr, const int* __restrict__ csr,
    const int* __restrict__ csrc, const int* __restrict__ orig,
    const float* __restrict__ H, float* __restrict__ AGG, int n) {
  int node = blockIdx.x * 4 + (threadIdx.x >> 6);
  int lane = threadIdx.x & 63;
  if (node >= n || lane >= 50) return;
  int o = orig[node];
  int b = rowptr[o];
  int deg = rowptr[o + 1] - b;

  auto fetchS = [&](int t, int &s, float &w) {
    if (t < deg) {
      int e = csr[b + t];
      int sv = csrc[e];
      s = (sv >= 0) ? sv : 0;
      w = (sv >= 0) ? 1.f : 0.f;
    } else {
      s = 0;
      w = 0.f;
    }
  };

  int s0, s1, s2;
  float w0, w1, w2;
  fetchS(0, s0, w0);
  fetchS(1, s1, w1);
  fetchS(2, s2, w2);
  float4 h0 = *(const float4*)(H + (size_t)s0 * 200 + 4 * lane);
  float4 h1 = *(const float4*)(H + (size_t)s1 * 200 + 4 * lane);
  float4 acc = make_float4(0.f, 0.f, 0.f, 0.f);
  for (int t = 0; t < deg; t++) {
    int s3;
    float w3;
    fetchS(t + 3, s3, w3);
    float4 h2 = *(const float4*)(H + (size_t)s2 * 200 + 4 * lane);
    acc.x = __fadd_rn(acc.x, __fmul_rn(w0, h0.x));
    acc.y = __fadd_rn(acc.y, __fmul_rn(w0, h0.y));
    acc.z = __fadd_rn(acc.z, __fmul_rn(w0, h0.z));
    acc.w = __fadd_rn(acc.w, __fmul_rn(w0, h0.w));
    h0 = h1; h1 = h2;
    w0 = w1; w1 = w2; w2 = w3;
    s2 = s3;
  }
  *(float4*)(AGG + (size_t)node * 200 + 4 * lane) = acc;
}

// score[i] = tanh((agg_i . Wrel + h_i . Wroot) + b)
__global__ __launch_bounds__(256) void score2_k(
    const float* __restrict__ AGG, const float* __restrict__ H,
    const float* __restrict__ wrel, const float* __restrict__ wroot,
    const float* __restrict__ bp, float* __restrict__ score, int n) {
  int node = blockIdx.x * 4 + (threadIdx.x >> 6);
  int lane = threadIdx.x & 63;
  if (node >= n) return;
  const float* arow = AGG + (size_t)node * 200;
  const float* hrow = H + (size_t)node * 200;
  float s1 = 0.f, s2 = 0.f;
  for (int d = lane; d < 200; d += 64) {
    s1 += arow[d] * wrel[d];
    s2 += hrow[d] * wroot[d];
  }
  for (int off = 32; off; off >>= 1) {
    s1 += __shfl_down(s1, off);
    s2 += __shfl_down(s2, off);
  }
  if (lane == 0) score[node] = tanhf((s1 + s2) + bp[0]);
}

// ---------------- O(n) exact rank (replaces O(n^2) rank_k) -------------------
// rank[i] = #{j : score[j] > score[i] || (score[j] == score[i] && j < i)}
// via: 2048-bucket histogram over order-preserving enc (11 high bits), then
// rank = (#elems in strictly-higher buckets) + (#same-bucket with larger key),
// key = (enc<<32)|~idx (distinct; unsigned compare == exact tie-break rule).
// -0.0 canonicalized to +0.0 so float equality semantics are preserved.
__global__ __launch_bounds__(256) void henc_k(const float* __restrict__ score,
                                              unsigned long long* __restrict__ keys,
                                              int* __restrict__ bins, int n) {
  int i = blockIdx.x * 256 + threadIdx.x;
  if (i >= n) return;
  unsigned b = __float_as_uint(score[i]);
  if (b == 0x80000000u) b = 0u;  // -0 -> +0
  unsigned enc = (b & 0x80000000u) ? ~b : (b | 0x80000000u);
  keys[i] = ((unsigned long long)enc << 32) | (unsigned)(~(unsigned)i);
  atomicAdd(&bins[enc >> 21], 1);
}

// single block: ascending exclusive scan of 2048 bins -> start, cursor
__global__ __launch_bounds__(256) void hscan_k(const int* __restrict__ bins,
                                               int* __restrict__ start,
                                               int* __restrict__ cursor) {
  __shared__ int psum[256];
  int t = threadIdx.x;
  int s = 0;
  for (int i = t * 8; i < t * 8 + 8; i++) s += bins[i];
  psum[t] = s;
  __syncthreads();
  if (t == 0) {
    int run = 0;
    for (int i = 0; i < 256; i++) { int v = psum[i]; psum[i] = run; run += v; }
  }
  __syncthreads();
  int run = psum[t];
  for (int i = t * 8; i < t * 8 + 8; i++) {
    start[i] = run;
    cursor[i] = run;
    run += bins[i];
  }
}

__global__ __launch_bounds__(256) void hplace_k(const unsigned long long* __restrict__ keys,
                                                int* __restrict__ cursor,
                                                int* __restrict__ members, int n) {
  int i = blockIdx.x * 256 + threadIdx.x;
  if (i >= n) return;
  int bu = (int)(keys[i] >> 53);
  members[atomicAdd(&cursor[bu], 1)] = i;
}

__global__ __launch_bounds__(256) void brank_k(const unsigned long long* __restrict__ keys,
                                               const int* __restrict__ start,
                                               const int* __restrict__ bins,
                                               const int* __restrict__ members,
                                               int* __restrict__ rank, int n) {
  int i = blockIdx.x * 256 + threadIdx.x;
  if (i >= n) return;
  unsigned long long ki = keys[i];
  int bu = (int)(ki >> 53);
  int b0 = start[bu], cb = bins[bu];
  int c = n - b0 - cb;  // all elements in strictly-higher buckets
  for (int m = b0; m < b0 + cb; m++) {
    c += (keys[members[m]] > ki) ? 1 : 0;
  }
  rank[i] = c;
}

__global__ __launch_bounds__(256) void perm_inv_k(const int* __restrict__ rank,
                                                  int* __restrict__ perm,
                                                  int* __restrict__ inv,
                                                  int n, int k) {
  int i = blockIdx.x * 256 + threadIdx.x;
  if (i >= n) return;
  int r = rank[i];
  if (r < k) { perm[r] = i; inv[i] = r; }
  else inv[i] = -1;
}

__global__ __launch_bounds__(256) void orig_update_k(const int* __restrict__ perm,
                                                     const int* __restrict__ oin,
                                                     int* __restrict__ oout, int k) {
  int r = blockIdx.x * 256 + threadIdx.x;
  if (r < k) oout[r] = oin[perm[r]];
}

__global__ __launch_bounds__(256) void gather_k(
    const float* __restrict__ H, const int* __restrict__ perm,
    const float* __restrict__ score, float* __restrict__ Ho, int k) {
  int r = blockIdx.x;
  int d = threadIdx.x;
  int p = perm[r];
  float s = score[p];
  if (d < 200) Ho[(size_t)r * 200 + d] = __fmul_rn(H[(size_t)p * 200 + d], s);
}

__global__ __launch_bounds__(256) void remap_k(int* __restrict__ cs,
                                               int* __restrict__ cd,
                                               const int* __restrict__ inv, int E) {
  int e = blockIdx.x * 256 + threadIdx.x;
  if (e >= E) return;
  int a = cs[e];
  if (a < 0) return;  // already invalid, stays invalid
  int na = inv[a], nb = inv[cd[e]];
  bool valid = (na >= 0) && (nb >= 0);
  cs[e] = valid ? na : -1;
  cd[e] = valid ? nb : -1;
}

__global__ __launch_bounds__(256) void out_copy_k(const float* __restrict__ h,
                                                  float* __restrict__ out, int cnt) {
  int t = blockIdx.x * 256 + threadIdx.x;
  if (t < cnt) out[t] = h[t];
}

// ---------------------------------------------------------------------------
extern "C" void kernel_launch(void* const* d_in, const int* in_sizes, int n_in,
                              void* d_out, int out_size, void* d_ws, size_t ws_size,
                              hipStream_t stream) {
  const int ID = 128, HD = 200;
  const int N = in_sizes[0] / ID;   // 50000
  const int E = in_sizes[1];        // 800000
  const int ET = E + N;
  const int total = N * HD;         // 10,000,000

  const float* x = (const float*)d_in[0];
  const int* src = (const int*)d_in[1];
  const int* dst = (const int*)d_in[2];
  const float* W[3]   = {(const float*)d_in[3], (const float*)d_in[7], (const float*)d_in[11]};
  const float* asv[3] = {(const float*)d_in[4], (const float*)d_in[8], (const float*)d_in[12]};
  const float* adv[3] = {(const float*)d_in[5], (const float*)d_in[9], (const float*)d_in[13]};
  const float* bv[3]  = {(const float*)d_in[6], (const float*)d_in[10], (const float*)d_in[14]};
  const float* Wrel  = (const float*)d_in[15];
  const float* Wroot = (const float*)d_in[16];
  const float* bpool = (const float*)d_in[17];

  char* ws = (char*)d_ws;
  float*    bufA  = (float*)(ws + 0);           // 40,000,000
  float*    bufB  = (float*)(ws + 40000000);    // 40,000,000
  float*    as_   = (float*)(ws + 80000000);    //   200,000
  float*    ad_   = (float*)(ws + 80200000);    //   200,000
  float*    ee_   = (float*)(ws + 80400000);    // 3,400,000
  unsigned* menc  = (unsigned*)(ws + 83800000); //   200,000
  float*    den   = (float*)(ws + 84000000);    //   200,000
  float*    score = (float*)(ws + 84200000);    //   200,000
  int*      rank_ = (int*)(ws + 84400000);      //   200,000 (also CSR count)
  int*      perm_ = (int*)(ws + 84600000);      //   200,000
  int*      inv_  = (int*)(ws + 84800000);      //   200,000
  int*      origA = (int*)(ws + 85000000);      //   200,000
  int*      origB = (int*)(ws + 85200000);      //   200,000
  int*      rowptr= (int*)(ws + 85400000);      //   250,000 (N+1 ints)
  int*      curs  = (int*)(ws + 85650000);      //   200,000
  int*      csr   = (int*)(ws + 85850000);      // 3,200,000
  int*      csrc  = (int*)(ws + 89050000);      // 3,200,000
  int*      cdst  = (int*)(ws + 92250000);      // 3,200,000  -> total 95.45 MB

  // Pooling-phase scratch reuses GAT-only regions (free once GAT layers done):
  unsigned long long* keys = (unsigned long long*)(ws + 80000000); // as_/ad_: 400,000 B = 8B*50000
  int* members = (int*)(ws + 83800000);  // menc region: 4B*50000
  int* bins    = (int*)(ws + 84000000);  // den region: 2048*4
  int* bstart  = bins + 2048;            //            2048*4
  int* bcur    = bins + 4096;            //            2048*4  (24,576 B total)

  // Host-side fold_in(key(42), i) = threefry2x32(k=(0,42), x=(0,i)).
  uint32_t fk0[3], fk1[3];
  for (int i = 0; i < 3; i++) {
    uint32_t a = 0u, b = (uint32_t)i;
    threefry2x32(0u, 42u, a, b);
    fk0[i] = a; fk1[i] = b;
  }

  const int B256 = 256;
  // ---------------- CSR build (once) ----------------
  hipMemsetAsync(rank_, 0, (size_t)N * 4, stream);
  indeg_k<<<(E + 255) / 256, B256, 0, stream>>>(dst, rank_, E);
  scan_k<<<1, B256, 0, stream>>>(rank_, rowptr, N);
  cpyint_k<<<(N + 255) / 256, B256, 0, stream>>>(rowptr, curs, N);
  place_k<<<(E + 255) / 256, B256, 0, stream>>>(dst, curs, csr, E);
  sortrow_k<<<(N + 255) / 256, B256, 0, stream>>>(rowptr, csr, N);

  // ---------------- 3 GAT layers ----------------
  for (int i = 0; i < 3; i++) {
    const float* in = (i == 0) ? x : bufB;
    int K = (i == 0) ? ID : HD;
    gemm200_k<<<(N + 127) / 128, B256, 0, stream>>>(in, W[i], bufA, N, K);
    dual_dot_k<<<(N + 3) / 4, B256, 0, stream>>>(bufA, asv[i], adv[i], as_, ad_, N);
    hipMemsetAsync(menc, 0, (size_t)N * 4, stream);
    edge_max_k<<<(ET + 255) / 256, B256, 0, stream>>>(src, dst, as_, ad_, menc, E, N);
    ee_k<<<(ET + 255) / 256, B256, 0, stream>>>(src, dst, as_, ad_, menc, ee_, E, N);
    den_k<<<(N + 255) / 256, B256, 0, stream>>>(rowptr, csr, ee_, den, E, N);
    alpha_k<<<(ET + 255) / 256, B256, 0, stream>>>(dst, den, ee_, E, N);
    gat_out_k<<<(N + 3) / 4, B256, 0, stream>>>(rowptr, csr, src, ee_, bufA, bufB, E, N);
    epi_k<<<(total + 255) / 256, B256, 0, stream>>>(bufB, bv[i], fk0[i], fk1[i], total);
  }

  // ---------------- SAGPooling loop ----------------
  einit_k<<<(E + 255) / 256, B256, 0, stream>>>(src, dst, csrc, cdst, origA, E, N);
  float* hcur = bufB;
  float* hnext = bufA;   // also serves as AGG scratch each round
  int* ocur = origA;
  int* onext = origB;
  int n = N;
  while (true) {
    int k = (n + 1) / 2;  // ceil(0.5 n)
    pool_agg_k<<<(n + 3) / 4, B256, 0, stream>>>(rowptr, csr, csrc, ocur, hcur, hnext, n);
    score2_k<<<(n + 3) / 4, B256, 0, stream>>>(hnext, hcur, Wrel, Wroot, bpool, score, n);
    // O(n) exact rank
    hipMemsetAsync(bins, 0, 2048 * 4, stream);
    henc_k<<<(n + 255) / 256, B256, 0, stream>>>(score, keys, bins, n);
    hscan_k<<<1, B256, 0, stream>>>(bins, bstart, bcur);
    hplace_k<<<(n + 255) / 256, B256, 0, stream>>>(keys, bcur, members, n);
    brank_k<<<(n + 255) / 256, B256, 0, stream>>>(keys, bstart, bins, members, rank_, n);
    perm_inv_k<<<(n + 255) / 256, B256, 0, stream>>>(rank_, perm_, inv_, n, k);
    orig_update_k<<<(k + 255) / 256, B256, 0, stream>>>(perm_, ocur, onext, k);
    gather_k<<<k, B256, 0, stream>>>(hcur, perm_, score, hnext, k);
    remap_k<<<(E + 255) / 256, B256, 0, stream>>>(csrc, cdst, inv_, E);
    { float* t = hcur; hcur = hnext; hnext = t; }
    { int* t = ocur; ocur = onext; onext = t; }
    n = k;
    if (n <= 512) break;
  }

  // ---------------- output: zeros(512,200) with first n rows = h -------------
  hipMemsetAsync(d_out, 0, (size_t)out_size * 4, stream);
  out_copy_k<<<(n * HD + 255) / 256, B256, 0, stream>>>(hcur, (float*)d_out, n * HD);
}

// Round 2
// 3055.146 us; speedup vs baseline: 5.3226x; 5.3226x over previous
//
#include <hip/hip_runtime.h>
#include <cstdint>
#include <cstddef>

// ---------------------------------------------------------------------------
// GAT x3 (exact JAX-threefry dropout, PARTITIONABLE mode) + SAGPool x7.
// Round 6:
//  * Round-5 bucketed rank blew up on tanh-saturated score ties (one bucket
//    held ~half the nodes -> O(B^2)). Replaced with a tie-proof stable LSD
//    radix sort (4 passes x 8 bits over order-preserving enc): position in
//    the stable descending sort IS the exact lax.top_k rank (ties by index).
//    Worst-case O(n), fully deterministic (scatter uses no atomics).
//  * gat_out_k / pool_agg_k keep the round-5 software pipeline (verified
//    improvement; gat_out left the top-5).
// All segment ops remain deterministic + np-association-matched (CSR serial).
// Workspace: ~95.5 MB (radix scratch reuses the GAT-phase ee_ region).
// ---------------------------------------------------------------------------

__host__ __device__ inline void tf_round(uint32_t &x0, uint32_t &x1, int r) {
  x0 += x1;
  x1 = (x1 << r) | (x1 >> (32 - r));
  x1 ^= x0;
}

// Exact jax threefry2x32 (Random123 KAT: key(0,0),ctr(0,0) -> 6b200159 99ba4efe)
__host__ __device__ inline void threefry2x32(uint32_t k0, uint32_t k1,
                                             uint32_t &x0, uint32_t &x1) {
  uint32_t ks2 = k0 ^ k1 ^ 0x1BD11BDAu;
  x0 += k0; x1 += k1;
  tf_round(x0, x1, 13); tf_round(x0, x1, 15); tf_round(x0, x1, 26); tf_round(x0, x1, 6);
  x0 += k1; x1 += ks2 + 1u;
  tf_round(x0, x1, 17); tf_round(x0, x1, 29); tf_round(x0, x1, 16); tf_round(x0, x1, 24);
  x0 += ks2; x1 += k0 + 2u;
  tf_round(x0, x1, 13); tf_round(x0, x1, 15); tf_round(x0, x1, 26); tf_round(x0, x1, 6);
  x0 += k0; x1 += k1 + 3u;
  tf_round(x0, x1, 17); tf_round(x0, x1, 29); tf_round(x0, x1, 16); tf_round(x0, x1, 24);
  x0 += k1; x1 += ks2 + 4u;
  tf_round(x0, x1, 13); tf_round(x0, x1, 15); tf_round(x0, x1, 26); tf_round(x0, x1, 6);
  x0 += ks2; x1 += k0 + 5u;
}

// ---------------- GEMM: C[M x 200] = A[M x K] @ B[K x 200], fp32 -------------
__global__ __launch_bounds__(256) void gemm200_k(
    const float* __restrict__ A, const float* __restrict__ B,
    float* __restrict__ C, int M, int K) {
  __shared__ __align__(16) float As[128 * 8];
  __shared__ __align__(16) float Bs[8][208];
  int tid = threadIdx.x;
  int m0 = blockIdx.x * 128;
  int r = tid >> 2;
  int colBase = (tid & 3) * 52;
  float acc0[52], acc1[52];
#pragma unroll
  for (int q = 0; q < 52; q++) { acc0[q] = 0.f; acc1[q] = 0.f; }

  for (int k0 = 0; k0 < K; k0 += 8) {
    {
      int row = tid >> 1;
      int c = (tid & 1) * 4;
      int gm = m0 + row;
      float4 v = make_float4(0.f, 0.f, 0.f, 0.f);
      if (gm < M) v = *(const float4*)(A + (size_t)gm * K + (k0 + c));
      *(float4*)(&As[row * 8 + c]) = v;
    }
    for (int t = tid; t < 400; t += 256) {
      int kk = t / 50;
      int c = (t - kk * 50) * 4;
      *(float4*)(&Bs[kk][c]) = *(const float4*)(B + (size_t)(k0 + kk) * 200 + c);
    }
    __syncthreads();
#pragma unroll
    for (int kk = 0; kk < 8; kk++) {
      float a0 = As[r * 8 + kk];
      float a1 = As[(r + 64) * 8 + kk];
#pragma unroll
      for (int q = 0; q < 13; q++) {
        float4 b = *(const float4*)(&Bs[kk][colBase + 4 * q]);
        acc0[4 * q + 0] += a0 * b.x; acc0[4 * q + 1] += a0 * b.y;
        acc0[4 * q + 2] += a0 * b.z; acc0[4 * q + 3] += a0 * b.w;
        acc1[4 * q + 0] += a1 * b.x; acc1[4 * q + 1] += a1 * b.y;
        acc1[4 * q + 2] += a1 * b.z; acc1[4 * q + 3] += a1 * b.w;
      }
    }
    __syncthreads();
  }
  int gm0 = m0 + r, gm1 = m0 + r + 64;
#pragma unroll
  for (int q = 0; q < 52; q++) {
    int col = colBase + q;
    if (col < 200) {
      if (gm0 < M) C[(size_t)gm0 * 200 + col] = acc0[q];
      if (gm1 < M) C[(size_t)gm1 * 200 + col] = acc1[q];
    }
  }
}

// ---------------- dual dot: o1[i]=H[i]·v1, o2[i]=H[i]·v2 (one wave/node) -----
__global__ __launch_bounds__(256) void dual_dot_k(
    const float* __restrict__ H, const float* __restrict__ v1,
    const float* __restrict__ v2, float* __restrict__ o1,
    float* __restrict__ o2, int n) {
  int wave = blockIdx.x * 4 + (threadIdx.x >> 6);
  int lane = threadIdx.x & 63;
  if (wave >= n) return;
  const float* row = H + (size_t)wave * 200;
  float s1 = 0.f, s2 = 0.f;
  for (int d = lane; d < 200; d += 64) {
    float h = row[d];
    s1 += h * v1[d];
    s2 += h * v2[d];
  }
  for (int off = 32; off; off >>= 1) {
    s1 += __shfl_down(s1, off);
    s2 += __shfl_down(s2, off);
  }
  if (lane == 0) { o1[wave] = s1; o2[wave] = s2; }
}

// ---------------- CSR build (dst-sorted, stable by edge index) ---------------
__global__ __launch_bounds__(256) void indeg_k(const int* __restrict__ dst,
                                               int* __restrict__ cnt, int E) {
  int e = blockIdx.x * 256 + threadIdx.x;
  if (e < E) atomicAdd(&cnt[dst[e]], 1);
}

// single block, 256 threads: exclusive scan cnt[0..N) -> rowptr[0..N]
__global__ __launch_bounds__(256) void scan_k(const int* __restrict__ cnt,
                                              int* __restrict__ rowptr, int N) {
  __shared__ int psum[256];
  int t = threadIdx.x;
  int CH = (N + 255) / 256;
  int beg = t * CH, end = min(beg + CH, N);
  if (beg > N) { beg = N; }
  int s = 0;
  for (int i = beg; i < end; i++) s += cnt[i];
  psum[t] = s;
  __syncthreads();
  if (t == 0) {
    int run = 0;
    for (int i = 0; i < 256; i++) { int v = psum[i]; psum[i] = run; run += v; }
  }
  __syncthreads();
  int run = psum[t];
  for (int i = beg; i < end; i++) { rowptr[i] = run; run += cnt[i]; }
  if (end == N && beg <= N) rowptr[N] = run;
}

__global__ __launch_bounds__(256) void cpyint_k(const int* __restrict__ a,
                                                int* __restrict__ b, int n) {
  int i = blockIdx.x * 256 + threadIdx.x;
  if (i < n) b[i] = a[i];
}

__global__ __launch_bounds__(256) void place_k(const int* __restrict__ dst,
                                               int* __restrict__ curs,
                                               int* __restrict__ csr, int E) {
  int e = blockIdx.x * 256 + threadIdx.x;
  if (e >= E) return;
  int pos = atomicAdd(&curs[dst[e]], 1);
  csr[pos] = e;
}

__global__ __launch_bounds__(256) void sortrow_k(const int* __restrict__ rowptr,
                                                 int* __restrict__ csr, int N) {
  int d = blockIdx.x * 256 + threadIdx.x;
  if (d >= N) return;
  int b = rowptr[d], e2 = rowptr[d + 1];
  for (int i = b + 1; i < e2; i++) {
    int v = csr[i];
    int j = i - 1;
    while (j >= b && csr[j] > v) { csr[j + 1] = csr[j]; j--; }
    csr[j + 1] = v;
  }
}

// ---------------- GAT edge softmax (deterministic, np order) -----------------
__device__ inline float dec_ord(unsigned enc) {
  unsigned b = (enc & 0x80000000u) ? (enc ^ 0x80000000u) : ~enc;
  return __uint_as_float(b);
}

__global__ __launch_bounds__(256) void edge_max_k(
    const int* __restrict__ src, const int* __restrict__ dst,
    const float* __restrict__ as_, const float* __restrict__ ad_,
    unsigned* __restrict__ menc, int E, int N) {
  int j = blockIdx.x * 256 + threadIdx.x;
  if (j >= E + N) return;
  int s, d;
  if (j < E) { s = src[j]; d = dst[j]; } else { s = j - E; d = s; }
  float v = as_[s] + ad_[d];
  float ev = (v >= 0.f) ? v : 0.2f * v;  // leaky_relu 0.2
  unsigned b = __float_as_uint(ev);
  unsigned enc = (b & 0x80000000u) ? ~b : (b | 0x80000000u);
  atomicMax(&menc[d], enc);
}

__global__ __launch_bounds__(256) void ee_k(
    const int* __restrict__ src, const int* __restrict__ dst,
    const float* __restrict__ as_, const float* __restrict__ ad_,
    const unsigned* __restrict__ menc, float* __restrict__ ee, int E, int N) {
  int j = blockIdx.x * 256 + threadIdx.x;
  if (j >= E + N) return;
  int s, d;
  if (j < E) { s = src[j]; d = dst[j]; } else { s = j - E; d = s; }
  float v = as_[s] + ad_[d];
  float ev = (v >= 0.f) ? v : 0.2f * v;
  ee[j] = expf(ev - dec_ord(menc[d]));
}

// denom per node: serial sum in edge-index order, self-loop (index E+d) LAST.
__global__ __launch_bounds__(256) void den_k(const int* __restrict__ rowptr,
                                             const int* __restrict__ csr,
                                             const float* __restrict__ ee,
                                             float* __restrict__ den, int E, int N) {
  int d = blockIdx.x * 256 + threadIdx.x;
  if (d >= N) return;
  float s = 0.f;
  int b = rowptr[d], e2 = rowptr[d + 1];
  for (int i = b; i < e2; i++) s = __fadd_rn(s, ee[csr[i]]);
  s = __fadd_rn(s, ee[E + d]);
  den[d] = s;
}

__global__ __launch_bounds__(256) void alpha_k(const int* __restrict__ dst,
                                               const float* __restrict__ den,
                                               float* __restrict__ ee, int E, int N) {
  int j = blockIdx.x * 256 + threadIdx.x;
  if (j >= E + N) return;
  int d = (j < E) ? dst[j] : (j - E);
  ee[j] = ee[j] / den[d];
}

// GAT out: wave per node, serial over edges (edge-index order, self last).
// Software-pipelined: index chain (csr->src/alpha) staged 3 slots ahead,
// 800B HW-row gather staged 2 slots ahead. Tail slots carry w=0 and, since
// acc starts at +0.0 and 0*finite = +/-0, the extra adds are exact no-ops:
// accumulation order/values are bitwise identical to the serial version.
__global__ __launch_bounds__(256) void gat_out_k(
    const int* __restrict__ rowptr, const int* __restrict__ csr,
    const int* __restrict__ src, const float* __restrict__ alpha,
    const float* __restrict__ HW, float* __restrict__ OUT, int E, int N) {
  int node = blockIdx.x * 4 + (threadIdx.x >> 6);
  int lane = threadIdx.x & 63;
  if (node >= N || lane >= 50) return;
  int b = rowptr[node];
  int deg = rowptr[node + 1] - b;
  int cnt = deg + 1;  // edges then self-loop (last)

  auto fetchS = [&](int t, int &s, float &w) {
    if (t < deg) {
      int e = csr[b + t];
      s = src[e];
      w = alpha[e];
    } else if (t == deg) {
      s = node;
      w = alpha[E + node];
    } else {
      s = node;  // valid dummy row
      w = 0.f;
    }
  };

  int s0, s1, s2;
  float w0, w1, w2;
  fetchS(0, s0, w0);
  fetchS(1, s1, w1);
  fetchS(2, s2, w2);
  float4 h0 = *(const float4*)(HW + (size_t)s0 * 200 + 4 * lane);
  float4 h1 = *(const float4*)(HW + (size_t)s1 * 200 + 4 * lane);
  float4 acc = make_float4(0.f, 0.f, 0.f, 0.f);
  for (int t = 0; t < cnt; t++) {
    int s3;
    float w3;
    fetchS(t + 3, s3, w3);
    float4 h2 = *(const float4*)(HW + (size_t)s2 * 200 + 4 * lane);
    acc.x = __fadd_rn(acc.x, __fmul_rn(w0, h0.x));
    acc.y = __fadd_rn(acc.y, __fmul_rn(w0, h0.y));
    acc.z = __fadd_rn(acc.z, __fmul_rn(w0, h0.z));
    acc.w = __fadd_rn(acc.w, __fmul_rn(w0, h0.w));
    h0 = h1; h1 = h2;
    w0 = w1; w1 = w2; w2 = w3;
    s2 = s3;
  }
  *(float4*)(OUT + (size_t)node * 200 + 4 * lane) = acc;
}

// -------- epilogue: bias + relu + JAX partitionable-threefry dropout ---------
__global__ __launch_bounds__(256) void epi_k(float* __restrict__ H,
                                             const float* __restrict__ bias,
                                             uint32_t k0, uint32_t k1, int total) {
  int t = blockIdx.x * 256 + threadIdx.x;
  if (t >= total) return;
  uint32_t x0 = 0u, x1 = (uint32_t)t;  // hi32(i)=0, lo32(i)=i  (i < 2^32)
  threefry2x32(k0, k1, x0, x1);
  uint32_t bits = x0 ^ x1;
  float u = __uint_as_float((bits >> 9) | 0x3f800000u) - 1.0f;
  int col = t % 200;
  float v = H[t] + bias[col];
  v = fmaxf(v, 0.f);
  H[t] = (u < 0.8f) ? (v / 0.8f) : 0.f;
}

// ---------------- pooling kernels -------------------------------------------
__global__ __launch_bounds__(256) void einit_k(
    const int* __restrict__ src, const int* __restrict__ dst,
    int* __restrict__ cs, int* __restrict__ cd, int* __restrict__ orig,
    int E, int N) {
  int e = blockIdx.x * 256 + threadIdx.x;
  if (e < E) { cs[e] = src[e]; cd[e] = dst[e]; }
  if (e < N) orig[e] = e;
}

// agg[d'] = sum over valid edges (orig CSR row of orig[d'], ascending e) of h[csrc[e]]
// Same software pipeline as gat_out_k; invalid edges contribute w=0 (exact no-op
// since acc starts +0.0, so association matches the skip-based serial version).
__global__ __launch_bounds__(256) void pool_agg_k(
    const int* __restrict__ rowptr, const int* __restrict__ csr,
    const int* __restrict__ csrc, const int* __restrict__ orig,
    const float* __restrict__ H, float* __restrict__ AGG, int n) {
  int node = blockIdx.x * 4 + (threadIdx.x >> 6);
  int lane = threadIdx.x & 63;
  if (node >= n || lane >= 50) return;
  int o = orig[node];
  int b = rowptr[o];
  int deg = rowptr[o + 1] - b;

  auto fetchS = [&](int t, int &s, float &w) {
    if (t < deg) {
      int e = csr[b + t];
      int sv = csrc[e];
      s = (sv >= 0) ? sv : 0;
      w = (sv >= 0) ? 1.f : 0.f;
    } else {
      s = 0;
      w = 0.f;
    }
  };

  int s0, s1, s2;
  float w0, w1, w2;
  fetchS(0, s0, w0);
  fetchS(1, s1, w1);
  fetchS(2, s2, w2);
  float4 h0 = *(const float4*)(H + (size_t)s0 * 200 + 4 * lane);
  float4 h1 = *(const float4*)(H + (size_t)s1 * 200 + 4 * lane);
  float4 acc = make_float4(0.f, 0.f, 0.f, 0.f);
  for (int t = 0; t < deg; t++) {
    int s3;
    float w3;
    fetchS(t + 3, s3, w3);
    float4 h2 = *(const float4*)(H + (size_t)s2 * 200 + 4 * lane);
    acc.x = __fadd_rn(acc.x, __fmul_rn(w0, h0.x));
    acc.y = __fadd_rn(acc.y, __fmul_rn(w0, h0.y));
    acc.z = __fadd_rn(acc.z, __fmul_rn(w0, h0.z));
    acc.w = __fadd_rn(acc.w, __fmul_rn(w0, h0.w));
    h0 = h1; h1 = h2;
    w0 = w1; w1 = w2; w2 = w3;
    s2 = s3;
  }
  *(float4*)(AGG + (size_t)node * 200 + 4 * lane) = acc;
}

// score[i] = tanh((agg_i . Wrel + h_i . Wroot) + b)
__global__ __launch_bounds__(256) void score2_k(
    const float* __restrict__ AGG, const float* __restrict__ H,
    const float* __restrict__ wrel, const float* __restrict__ wroot,
    const float* __restrict__ bp, float* __restrict__ score, int n) {
  int node = blockIdx.x * 4 + (threadIdx.x >> 6);
  int lane = threadIdx.x & 63;
  if (node >= n) return;
  const float* arow = AGG + (size_t)node * 200;
  const float* hrow = H + (size_t)node * 200;
  float s1 = 0.f, s2 = 0.f;
  for (int d = lane; d < 200; d += 64) {
    s1 += arow[d] * wrel[d];
    s2 += hrow[d] * wroot[d];
  }
  for (int off = 32; off; off >>= 1) {
    s1 += __shfl_down(s1, off);
    s2 += __shfl_down(s2, off);
  }
  if (lane == 0) score[node] = tanhf((s1 + s2) + bp[0]);
}

// ---------------- stable LSD radix sort -> exact lax.top_k rank --------------
// Stable ascending sort on ~enc (= descending score, ties by original index
// ascending): sorted position r IS rank[i] under
//   rank[i] = #{j : s_j > s_i || (s_j == s_i && j < i)}.
// Tie-proof: O(n) regardless of score distribution (tanh saturation safe).
// -0.0 canonicalized to +0.0 so float equality semantics are preserved.
__global__ __launch_bounds__(256) void renc_k(const float* __restrict__ score,
                                              unsigned* __restrict__ keyA,
                                              int* __restrict__ payA, int n) {
  int i = blockIdx.x * 256 + threadIdx.x;
  if (i >= n) return;
  unsigned b = __float_as_uint(score[i]);
  if (b == 0x80000000u) b = 0u;  // -0 -> +0
  unsigned enc = (b & 0x80000000u) ? ~b : (b | 0x80000000u);
  keyA[i] = ~enc;  // ascending sort of ~enc == descending score
  payA[i] = i;
}

// counts[digit * NB + block] = #elements in block with this digit
__global__ __launch_bounds__(256) void rhist_k(const unsigned* __restrict__ key,
                                               int* __restrict__ counts,
                                               int n, int NB, int shift) {
  __shared__ int hist[256];
  hist[threadIdx.x] = 0;
  __syncthreads();
  int i = blockIdx.x * 256 + threadIdx.x;
  if (i < n) atomicAdd(&hist[(key[i] >> shift) & 255u], 1);
  __syncthreads();
  counts[threadIdx.x * NB + blockIdx.x] = hist[threadIdx.x];
}

// single block: exclusive scan of counts in digit-major, block-minor order
__global__ __launch_bounds__(256) void rscan_k(const int* __restrict__ counts,
                                               int* __restrict__ base, int NB) {
  __shared__ int tot[256];
  int t = threadIdx.x;
  int s = 0;
  for (int b = 0; b < NB; b++) s += counts[t * NB + b];
  tot[t] = s;
  __syncthreads();
  if (t == 0) {
    int run = 0;
    for (int i = 0; i < 256; i++) { int v = tot[i]; tot[i] = run; run += v; }
  }
  __syncthreads();
  int run = tot[t];
  for (int b = 0; b < NB; b++) { base[t * NB + b] = run; run += counts[t * NB + b]; }
}

// stable scatter: within-block offset = #earlier threads with same digit
// (no atomics -> deterministic & stable across any scheduling)
__global__ __launch_bounds__(256) void rscatter_k(
    const unsigned* __restrict__ keyIn, const int* __restrict__ payIn,
    const int* __restrict__ base, unsigned* __restrict__ keyOut,
    int* __restrict__ payOut, int n, int NB, int shift) {
  __shared__ int dig[256];
  int t = threadIdx.x;
  int i = blockIdx.x * 256 + t;
  unsigned k = 0u;
  int p = 0, d = -1;
  if (i < n) {
    k = keyIn[i];
    p = payIn[i];
    d = (int)((k >> shift) & 255u);
  }
  dig[t] = d;
  __syncthreads();
  if (i < n) {
    int local = 0;
    for (int j = 0; j < t; j++) local += (dig[j] == d) ? 1 : 0;
    int pos = base[d * NB + blockIdx.x] + local;
    keyOut[pos] = k;
    payOut[pos] = p;
  }
}

// sorted position -> perm/inv (identical semantics to old rank<k selection)
__global__ __launch_bounds__(256) void ranksort_k(const int* __restrict__ pay,
                                                  int* __restrict__ perm,
                                                  int* __restrict__ inv,
                                                  int n, int k) {
  int r = blockIdx.x * 256 + threadIdx.x;
  if (r >= n) return;
  int i = pay[r];
  if (r < k) { perm[r] = i; inv[i] = r; }
  else inv[i] = -1;
}

__global__ __launch_bounds__(256) void orig_update_k(const int* __restrict__ perm,
                                                     const int* __restrict__ oin,
                                                     int* __restrict__ oout, int k) {
  int r = blockIdx.x * 256 + threadIdx.x;
  if (r < k) oout[r] = oin[perm[r]];
}

__global__ __launch_bounds__(256) void gather_k(
    const float* __restrict__ H, const int* __restrict__ perm,
    const float* __restrict__ score, float* __restrict__ Ho, int k) {
  int r = blockIdx.x;
  int d = threadIdx.x;
  int p = perm[r];
  float s = score[p];
  if (d < 200) Ho[(size_t)r * 200 + d] = __fmul_rn(H[(size_t)p * 200 + d], s);
}

__global__ __launch_bounds__(256) void remap_k(int* __restrict__ cs,
                                               int* __restrict__ cd,
                                               const int* __restrict__ inv, int E) {
  int e = blockIdx.x * 256 + threadIdx.x;
  if (e >= E) return;
  int a = cs[e];
  if (a < 0) return;  // already invalid, stays invalid
  int na = inv[a], nb = inv[cd[e]];
  bool valid = (na >= 0) && (nb >= 0);
  cs[e] = valid ? na : -1;
  cd[e] = valid ? nb : -1;
}

__global__ __launch_bounds__(256) void out_copy_k(const float* __restrict__ h,
                                                  float* __restrict__ out, int cnt) {
  int t = blockIdx.x * 256 + threadIdx.x;
  if (t < cnt) out[t] = h[t];
}

// ---------------------------------------------------------------------------
extern "C" void kernel_launch(void* const* d_in, const int* in_sizes, int n_in,
                              void* d_out, int out_size, void* d_ws, size_t ws_size,
                              hipStream_t stream) {
  const int ID = 128, HD = 200;
  const int N = in_sizes[0] / ID;   // 50000
  const int E = in_sizes[1];        // 800000
  const int ET = E + N;
  const int total = N * HD;         // 10,000,000

  const float* x = (const float*)d_in[0];
  const int* src = (const int*)d_in[1];
  const int* dst = (const int*)d_in[2];
  const float* W[3]   = {(const float*)d_in[3], (const float*)d_in[7], (const float*)d_in[11]};
  const float* asv[3] = {(const float*)d_in[4], (const float*)d_in[8], (const float*)d_in[12]};
  const float* adv[3] = {(const float*)d_in[5], (const float*)d_in[9], (const float*)d_in[13]};
  const float* bv[3]  = {(const float*)d_in[6], (const float*)d_in[10], (const float*)d_in[14]};
  const float* Wrel  = (const float*)d_in[15];
  const float* Wroot = (const float*)d_in[16];
  const float* bpool = (const float*)d_in[17];

  char* ws = (char*)d_ws;
  float*    bufA  = (float*)(ws + 0);           // 40,000,000
  float*    bufB  = (float*)(ws + 40000000);    // 40,000,000
  float*    as_   = (float*)(ws + 80000000);    //   200,000
  float*    ad_   = (float*)(ws + 80200000);    //   200,000
  float*    ee_   = (float*)(ws + 80400000);    // 3,400,000
  unsigned* menc  = (unsigned*)(ws + 83800000); //   200,000
  float*    den   = (float*)(ws + 84000000);    //   200,000
  float*    score = (float*)(ws + 84200000);    //   200,000
  int*      rank_ = (int*)(ws + 84400000);      //   200,000 (CSR count scratch)
  int*      perm_ = (int*)(ws + 84600000);      //   200,000
  int*      inv_  = (int*)(ws + 84800000);      //   200,000
  int*      origA = (int*)(ws + 85000000);      //   200,000
  int*      origB = (int*)(ws + 85200000);      //   200,000
  int*      rowptr= (int*)(ws + 85400000);      //   250,000 (N+1 ints)
  int*      curs  = (int*)(ws + 85650000);      //   200,000
  int*      csr   = (int*)(ws + 85850000);      // 3,200,000
  int*      csrc  = (int*)(ws + 89050000);      // 3,200,000
  int*      cdst  = (int*)(ws + 92250000);      // 3,200,000  -> total 95.45 MB

  // Radix scratch reuses the GAT-only ee_ region (free during pooling):
  // six 256 KiB slots: keyA keyB payA payB counts base (NB<=196 -> 200,704 B)
  char* rx = ws + 80400000;
  unsigned* keyA   = (unsigned*)(rx + 0 * 262144);
  unsigned* keyB   = (unsigned*)(rx + 1 * 262144);
  int*      payA   = (int*)(rx + 2 * 262144);
  int*      payB   = (int*)(rx + 3 * 262144);
  int*      rcounts= (int*)(rx + 4 * 262144);
  int*      rbase  = (int*)(rx + 5 * 262144);

  // Host-side fold_in(key(42), i) = threefry2x32(k=(0,42), x=(0,i)).
  uint32_t fk0[3], fk1[3];
  for (int i = 0; i < 3; i++) {
    uint32_t a = 0u, b = (uint32_t)i;
    threefry2x32(0u, 42u, a, b);
    fk0[i] = a; fk1[i] = b;
  }

  const int B256 = 256;
  // ---------------- CSR build (once) ----------------
  hipMemsetAsync(rank_, 0, (size_t)N * 4, stream);
  indeg_k<<<(E + 255) / 256, B256, 0, stream>>>(dst, rank_, E);
  scan_k<<<1, B256, 0, stream>>>(rank_, rowptr, N);
  cpyint_k<<<(N + 255) / 256, B256, 0, stream>>>(rowptr, curs, N);
  place_k<<<(E + 255) / 256, B256, 0, stream>>>(dst, curs, csr, E);
  sortrow_k<<<(N + 255) / 256, B256, 0, stream>>>(rowptr, csr, N);

  // ---------------- 3 GAT layers ----------------
  for (int i = 0; i < 3; i++) {
    const float* in = (i == 0) ? x : bufB;
    int K = (i == 0) ? ID : HD;
    gemm200_k<<<(N + 127) / 128, B256, 0, stream>>>(in, W[i], bufA, N, K);
    dual_dot_k<<<(N + 3) / 4, B256, 0, stream>>>(bufA, asv[i], adv[i], as_, ad_, N);
    hipMemsetAsync(menc, 0, (size_t)N * 4, stream);
    edge_max_k<<<(ET + 255) / 256, B256, 0, stream>>>(src, dst, as_, ad_, menc, E, N);
    ee_k<<<(ET + 255) / 256, B256, 0, stream>>>(src, dst, as_, ad_, menc, ee_, E, N);
    den_k<<<(N + 255) / 256, B256, 0, stream>>>(rowptr, csr, ee_, den, E, N);
    alpha_k<<<(ET + 255) / 256, B256, 0, stream>>>(dst, den, ee_, E, N);
    gat_out_k<<<(N + 3) / 4, B256, 0, stream>>>(rowptr, csr, src, ee_, bufA, bufB, E, N);
    epi_k<<<(total + 255) / 256, B256, 0, stream>>>(bufB, bv[i], fk0[i], fk1[i], total);
  }

  // ---------------- SAGPooling loop ----------------
  einit_k<<<(E + 255) / 256, B256, 0, stream>>>(src, dst, csrc, cdst, origA, E, N);
  float* hcur = bufB;
  float* hnext = bufA;   // also serves as AGG scratch each round
  int* ocur = origA;
  int* onext = origB;
  int n = N;
  while (true) {
    int k = (n + 1) / 2;  // ceil(0.5 n)
    int NB = (n + 255) / 256;
    pool_agg_k<<<(n + 3) / 4, B256, 0, stream>>>(rowptr, csr, csrc, ocur, hcur, hnext, n);
    score2_k<<<(n + 3) / 4, B256, 0, stream>>>(hnext, hcur, Wrel, Wroot, bpool, score, n);
    // exact rank via stable 4x8-bit LSD radix sort (tie-proof, O(n))
    renc_k<<<NB, B256, 0, stream>>>(score, keyA, payA, n);
    unsigned* ki = keyA; unsigned* ko = keyB;
    int* pi = payA; int* po = payB;
    for (int pass = 0; pass < 4; pass++) {
      int shift = pass * 8;
      rhist_k<<<NB, B256, 0, stream>>>(ki, rcounts, n, NB, shift);
      rscan_k<<<1, B256, 0, stream>>>(rcounts, rbase, NB);
      rscatter_k<<<NB, B256, 0, stream>>>(ki, pi, rbase, ko, po, n, NB, shift);
      { unsigned* t = ki; ki = ko; ko = t; }
      { int* t = pi; pi = po; po = t; }
    }
    ranksort_k<<<NB, B256, 0, stream>>>(pi, perm_, inv_, n, k);
    orig_update_k<<<(k + 255) / 256, B256, 0, stream>>>(perm_, ocur, onext, k);
    gather_k<<<k, B256, 0, stream>>>(hcur, perm_, score, hnext, k);
    remap_k<<<(E + 255) / 256, B256, 0, stream>>>(csrc, cdst, inv_, E);
    { float* t = hcur; hcur = hnext; hnext = t; }
    { int* t = ocur; ocur = onext; onext = t; }
    n = k;
    if (n <= 512) break;
  }

  // ---------------- output: zeros(512,200) with first n rows = h -------------
  hipMemsetAsync(d_out, 0, (size_t)out_size * 4, stream);
  out_copy_k<<<(n * HD + 255) / 256, B256, 0, stream>>>(hcur, (float*)d_out, n * HD);
}

// Round 3
// 2625.307 us; speedup vs baseline: 6.1941x; 1.1637x over previous
//
#include <hip/hip_runtime.h>
#include <cstdint>
#include <cstddef>

// ---------------------------------------------------------------------------
// GAT x3 (exact JAX-threefry dropout, PARTITIONABLE mode) + SAGPool x7.
// Round 7:
//  * gemm200_k: float4 epilogue stores (was 52 scalar stores/thread -> 7x HBM
//    write amplification, 280MB vs 40MB actual C), register prefetch of next
//    k-tile (overlap global latency with compute), As padded 8->9 floats
//    (kills 4-way LDS bank conflict on a0/a1 reads). FMA accumulation order
//    per output element unchanged (k ascending) -> bitwise-identical results.
//  * Radix: renc fused into pass-0 hist; final scatter writes perm/inv/oout
//    directly (position in stable sort == rank). -3 launches/pool iteration.
//  * gat_out_k / pool_agg_k keep the round-5 software pipeline (verified).
// All segment ops remain deterministic + np-association-matched (CSR serial).
// Workspace: ~95.5 MB (radix scratch reuses the GAT-phase ee_ region).
// ---------------------------------------------------------------------------

__host__ __device__ inline void tf_round(uint32_t &x0, uint32_t &x1, int r) {
  x0 += x1;
  x1 = (x1 << r) | (x1 >> (32 - r));
  x1 ^= x0;
}

// Exact jax threefry2x32 (Random123 KAT: key(0,0),ctr(0,0) -> 6b200159 99ba4efe)
__host__ __device__ inline void threefry2x32(uint32_t k0, uint32_t k1,
                                             uint32_t &x0, uint32_t &x1) {
  uint32_t ks2 = k0 ^ k1 ^ 0x1BD11BDAu;
  x0 += k0; x1 += k1;
  tf_round(x0, x1, 13); tf_round(x0, x1, 15); tf_round(x0, x1, 26); tf_round(x0, x1, 6);
  x0 += k1; x1 += ks2 + 1u;
  tf_round(x0, x1, 17); tf_round(x0, x1, 29); tf_round(x0, x1, 16); tf_round(x0, x1, 24);
  x0 += ks2; x1 += k0 + 2u;
  tf_round(x0, x1, 13); tf_round(x0, x1, 15); tf_round(x0, x1, 26); tf_round(x0, x1, 6);
  x0 += k0; x1 += k1 + 3u;
  tf_round(x0, x1, 17); tf_round(x0, x1, 29); tf_round(x0, x1, 16); tf_round(x0, x1, 24);
  x0 += k1; x1 += ks2 + 4u;
  tf_round(x0, x1, 13); tf_round(x0, x1, 15); tf_round(x0, x1, 26); tf_round(x0, x1, 6);
  x0 += ks2; x1 += k0 + 5u;
}

// ---------------- GEMM: C[M x 200] = A[M x K] @ B[K x 200], fp32 -------------
// 128-row x 200-col tile, 256 threads; thread owns rows {r, r+64}, col quarter
// colBase..colBase+51 (last quarter: 44 valid cols = 11 float4s).
__global__ __launch_bounds__(256) void gemm200_k(
    const float* __restrict__ A, const float* __restrict__ B,
    float* __restrict__ C, int M, int K) {
  __shared__ float As[128 * 9];                 // pad 8->9: conflict-free reads
  __shared__ __align__(16) float Bs[8][208];
  int tid = threadIdx.x;
  int m0 = blockIdx.x * 128;
  int r = tid >> 2;
  int colBase = (tid & 3) * 52;
  int nq = (colBase == 156) ? 11 : 13;          // valid float4s in epilogue
  float acc0[52], acc1[52];
#pragma unroll
  for (int q = 0; q < 52; q++) { acc0[q] = 0.f; acc1[q] = 0.f; }

  // staging assignments
  int arow = tid >> 1;
  int ac = (tid & 1) * 4;
  int gmA = m0 + arow;
  const float* Aptr = A + (size_t)gmA * K + ac;
  int bk0 = tid / 50, bc0 = (tid - bk0 * 50) * 4;
  int t2 = tid + 256;
  int bk1 = t2 / 50, bc1 = (t2 - bk1 * 50) * 4;
  bool hasB1 = (t2 < 400);

  // prefetch tile 0 into registers
  float4 va = make_float4(0.f, 0.f, 0.f, 0.f);
  if (gmA < M) va = *(const float4*)(Aptr);
  float4 vb0 = *(const float4*)(B + (size_t)bk0 * 200 + bc0);
  float4 vb1 = make_float4(0.f, 0.f, 0.f, 0.f);
  if (hasB1) vb1 = *(const float4*)(B + (size_t)bk1 * 200 + bc1);

  for (int k0 = 0; k0 < K; k0 += 8) {
    // commit staged registers to LDS
    As[arow * 9 + ac + 0] = va.x;
    As[arow * 9 + ac + 1] = va.y;
    As[arow * 9 + ac + 2] = va.z;
    As[arow * 9 + ac + 3] = va.w;
    *(float4*)(&Bs[bk0][bc0]) = vb0;
    if (hasB1) *(float4*)(&Bs[bk1][bc1]) = vb1;
    __syncthreads();
    // issue next-tile global loads; they land under the FMA phase below
    int kn = k0 + 8;
    if (kn < K) {
      if (gmA < M) va = *(const float4*)(Aptr + kn);
      vb0 = *(const float4*)(B + (size_t)(kn + bk0) * 200 + bc0);
      if (hasB1) vb1 = *(const float4*)(B + (size_t)(kn + bk1) * 200 + bc1);
    }
#pragma unroll
    for (int kk = 0; kk < 8; kk++) {
      float a0 = As[r * 9 + kk];
      float a1 = As[(r + 64) * 9 + kk];
#pragma unroll
      for (int q = 0; q < 13; q++) {
        float4 b = *(const float4*)(&Bs[kk][colBase + 4 * q]);
        acc0[4 * q + 0] += a0 * b.x; acc0[4 * q + 1] += a0 * b.y;
        acc0[4 * q + 2] += a0 * b.z; acc0[4 * q + 3] += a0 * b.w;
        acc1[4 * q + 0] += a1 * b.x; acc1[4 * q + 1] += a1 * b.y;
        acc1[4 * q + 2] += a1 * b.z; acc1[4 * q + 3] += a1 * b.w;
      }
    }
    __syncthreads();
  }
  // epilogue: coalesced float4 stores (each 64B line filled by one thread in
  // 4 consecutive instructions -> no partial-line HBM write amplification)
  int gm0 = m0 + r, gm1 = m0 + r + 64;
#pragma unroll
  for (int q = 0; q < 13; q++) {
    if (q < nq) {
      int col = colBase + 4 * q;
      float4 v0 = make_float4(acc0[4 * q + 0], acc0[4 * q + 1],
                              acc0[4 * q + 2], acc0[4 * q + 3]);
      float4 v1 = make_float4(acc1[4 * q + 0], acc1[4 * q + 1],
                              acc1[4 * q + 2], acc1[4 * q + 3]);
      if (gm0 < M) *(float4*)(C + (size_t)gm0 * 200 + col) = v0;
      if (gm1 < M) *(float4*)(C + (size_t)gm1 * 200 + col) = v1;
    }
  }
}

// ---------------- dual dot: o1[i]=H[i]·v1, o2[i]=H[i]·v2 (one wave/node) -----
__global__ __launch_bounds__(256) void dual_dot_k(
    const float* __restrict__ H, const float* __restrict__ v1,
    const float* __restrict__ v2, float* __restrict__ o1,
    float* __restrict__ o2, int n) {
  int wave = blockIdx.x * 4 + (threadIdx.x >> 6);
  int lane = threadIdx.x & 63;
  if (wave >= n) return;
  const float* row = H + (size_t)wave * 200;
  float s1 = 0.f, s2 = 0.f;
  for (int d = lane; d < 200; d += 64) {
    float h = row[d];
    s1 += h * v1[d];
    s2 += h * v2[d];
  }
  for (int off = 32; off; off >>= 1) {
    s1 += __shfl_down(s1, off);
    s2 += __shfl_down(s2, off);
  }
  if (lane == 0) { o1[wave] = s1; o2[wave] = s2; }
}

// ---------------- CSR build (dst-sorted, stable by edge index) ---------------
__global__ __launch_bounds__(256) void indeg_k(const int* __restrict__ dst,
                                               int* __restrict__ cnt, int E) {
  int e = blockIdx.x * 256 + threadIdx.x;
  if (e < E) atomicAdd(&cnt[dst[e]], 1);
}

// single block, 256 threads: exclusive scan cnt[0..N) -> rowptr[0..N]
__global__ __launch_bounds__(256) void scan_k(const int* __restrict__ cnt,
                                              int* __restrict__ rowptr, int N) {
  __shared__ int psum[256];
  int t = threadIdx.x;
  int CH = (N + 255) / 256;
  int beg = t * CH, end = min(beg + CH, N);
  if (beg > N) { beg = N; }
  int s = 0;
  for (int i = beg; i < end; i++) s += cnt[i];
  psum[t] = s;
  __syncthreads();
  if (t == 0) {
    int run = 0;
    for (int i = 0; i < 256; i++) { int v = psum[i]; psum[i] = run; run += v; }
  }
  __syncthreads();
  int run = psum[t];
  for (int i = beg; i < end; i++) { rowptr[i] = run; run += cnt[i]; }
  if (end == N && beg <= N) rowptr[N] = run;
}

__global__ __launch_bounds__(256) void cpyint_k(const int* __restrict__ a,
                                                int* __restrict__ b, int n) {
  int i = blockIdx.x * 256 + threadIdx.x;
  if (i < n) b[i] = a[i];
}

__global__ __launch_bounds__(256) void place_k(const int* __restrict__ dst,
                                               int* __restrict__ curs,
                                               int* __restrict__ csr, int E) {
  int e = blockIdx.x * 256 + threadIdx.x;
  if (e >= E) return;
  int pos = atomicAdd(&curs[dst[e]], 1);
  csr[pos] = e;
}

__global__ __launch_bounds__(256) void sortrow_k(const int* __restrict__ rowptr,
                                                 int* __restrict__ csr, int N) {
  int d = blockIdx.x * 256 + threadIdx.x;
  if (d >= N) return;
  int b = rowptr[d], e2 = rowptr[d + 1];
  for (int i = b + 1; i < e2; i++) {
    int v = csr[i];
    int j = i - 1;
    while (j >= b && csr[j] > v) { csr[j + 1] = csr[j]; j--; }
    csr[j + 1] = v;
  }
}

// ---------------- GAT edge softmax (deterministic, np order) -----------------
__device__ inline float dec_ord(unsigned enc) {
  unsigned b = (enc & 0x80000000u) ? (enc ^ 0x80000000u) : ~enc;
  return __uint_as_float(b);
}

__global__ __launch_bounds__(256) void edge_max_k(
    const int* __restrict__ src, const int* __restrict__ dst,
    const float* __restrict__ as_, const float* __restrict__ ad_,
    unsigned* __restrict__ menc, int E, int N) {
  int j = blockIdx.x * 256 + threadIdx.x;
  if (j >= E + N) return;
  int s, d;
  if (j < E) { s = src[j]; d = dst[j]; } else { s = j - E; d = s; }
  float v = as_[s] + ad_[d];
  float ev = (v >= 0.f) ? v : 0.2f * v;  // leaky_relu 0.2
  unsigned b = __float_as_uint(ev);
  unsigned enc = (b & 0x80000000u) ? ~b : (b | 0x80000000u);
  atomicMax(&menc[d], enc);
}

__global__ __launch_bounds__(256) void ee_k(
    const int* __restrict__ src, const int* __restrict__ dst,
    const float* __restrict__ as_, const float* __restrict__ ad_,
    const unsigned* __restrict__ menc, float* __restrict__ ee, int E, int N) {
  int j = blockIdx.x * 256 + threadIdx.x;
  if (j >= E + N) return;
  int s, d;
  if (j < E) { s = src[j]; d = dst[j]; } else { s = j - E; d = s; }
  float v = as_[s] + ad_[d];
  float ev = (v >= 0.f) ? v : 0.2f * v;
  ee[j] = expf(ev - dec_ord(menc[d]));
}

// denom per node: serial sum in edge-index order, self-loop (index E+d) LAST.
__global__ __launch_bounds__(256) void den_k(const int* __restrict__ rowptr,
                                             const int* __restrict__ csr,
                                             const float* __restrict__ ee,
                                             float* __restrict__ den, int E, int N) {
  int d = blockIdx.x * 256 + threadIdx.x;
  if (d >= N) return;
  float s = 0.f;
  int b = rowptr[d], e2 = rowptr[d + 1];
  for (int i = b; i < e2; i++) s = __fadd_rn(s, ee[csr[i]]);
  s = __fadd_rn(s, ee[E + d]);
  den[d] = s;
}

__global__ __launch_bounds__(256) void alpha_k(const int* __restrict__ dst,
                                               const float* __restrict__ den,
                                               float* __restrict__ ee, int E, int N) {
  int j = blockIdx.x * 256 + threadIdx.x;
  if (j >= E + N) return;
  int d = (j < E) ? dst[j] : (j - E);
  ee[j] = ee[j] / den[d];
}

// GAT out: wave per node, serial over edges (edge-index order, self last).
// Software-pipelined: index chain (csr->src/alpha) staged 3 slots ahead,
// 800B HW-row gather staged 2 slots ahead. Tail slots carry w=0 and, since
// acc starts at +0.0 and 0*finite = +/-0, the extra adds are exact no-ops:
// accumulation order/values are bitwise identical to the serial version.
__global__ __launch_bounds__(256) void gat_out_k(
    const int* __restrict__ rowptr, const int* __restrict__ csr,
    const int* __restrict__ src, const float* __restrict__ alpha,
    const float* __restrict__ HW, float* __restrict__ OUT, int E, int N) {
  int node = blockIdx.x * 4 + (threadIdx.x >> 6);
  int lane = threadIdx.x & 63;
  if (node >= N || lane >= 50) return;
  int b = rowptr[node];
  int deg = rowptr[node + 1] - b;
  int cnt = deg + 1;  // edges then self-loop (last)

  auto fetchS = [&](int t, int &s, float &w) {
    if (t < deg) {
      int e = csr[b + t];
      s = src[e];
      w = alpha[e];
    } else if (t == deg) {
      s = node;
      w = alpha[E + node];
    } else {
      s = node;  // valid dummy row
      w = 0.f;
    }
  };

  int s0, s1, s2;
  float w0, w1, w2;
  fetchS(0, s0, w0);
  fetchS(1, s1, w1);
  fetchS(2, s2, w2);
  float4 h0 = *(const float4*)(HW + (size_t)s0 * 200 + 4 * lane);
  float4 h1 = *(const float4*)(HW + (size_t)s1 * 200 + 4 * lane);
  float4 acc = make_float4(0.f, 0.f, 0.f, 0.f);
  for (int t = 0; t < cnt; t++) {
    int s3;
    float w3;
    fetchS(t + 3, s3, w3);
    float4 h2 = *(const float4*)(HW + (size_t)s2 * 200 + 4 * lane);
    acc.x = __fadd_rn(acc.x, __fmul_rn(w0, h0.x));
    acc.y = __fadd_rn(acc.y, __fmul_rn(w0, h0.y));
    acc.z = __fadd_rn(acc.z, __fmul_rn(w0, h0.z));
    acc.w = __fadd_rn(acc.w, __fmul_rn(w0, h0.w));
    h0 = h1; h1 = h2;
    w0 = w1; w1 = w2; w2 = w3;
    s2 = s3;
  }
  *(float4*)(OUT + (size_t)node * 200 + 4 * lane) = acc;
}

// -------- epilogue: bias + relu + JAX partitionable-threefry dropout ---------
__global__ __launch_bounds__(256) void epi_k(float* __restrict__ H,
                                             const float* __restrict__ bias,
                                             uint32_t k0, uint32_t k1, int total) {
  int t = blockIdx.x * 256 + threadIdx.x;
  if (t >= total) return;
  uint32_t x0 = 0u, x1 = (uint32_t)t;  // hi32(i)=0, lo32(i)=i  (i < 2^32)
  threefry2x32(k0, k1, x0, x1);
  uint32_t bits = x0 ^ x1;
  float u = __uint_as_float((bits >> 9) | 0x3f800000u) - 1.0f;
  int col = t % 200;
  float v = H[t] + bias[col];
  v = fmaxf(v, 0.f);
  H[t] = (u < 0.8f) ? (v / 0.8f) : 0.f;
}

// ---------------- pooling kernels -------------------------------------------
__global__ __launch_bounds__(256) void einit_k(
    const int* __restrict__ src, const int* __restrict__ dst,
    int* __restrict__ cs, int* __restrict__ cd, int* __restrict__ orig,
    int E, int N) {
  int e = blockIdx.x * 256 + threadIdx.x;
  if (e < E) { cs[e] = src[e]; cd[e] = dst[e]; }
  if (e < N) orig[e] = e;
}

// agg[d'] = sum over valid edges (orig CSR row of orig[d'], ascending e) of h[csrc[e]]
// Same software pipeline as gat_out_k; invalid edges contribute w=0 (exact no-op
// since acc starts +0.0, so association matches the skip-based serial version).
__global__ __launch_bounds__(256) void pool_agg_k(
    const int* __restrict__ rowptr, const int* __restrict__ csr,
    const int* __restrict__ csrc, const int* __restrict__ orig,
    const float* __restrict__ H, float* __restrict__ AGG, int n) {
  int node = blockIdx.x * 4 + (threadIdx.x >> 6);
  int lane = threadIdx.x & 63;
  if (node >= n || lane >= 50) return;
  int o = orig[node];
  int b = rowptr[o];
  int deg = rowptr[o + 1] - b;

  auto fetchS = [&](int t, int &s, float &w) {
    if (t < deg) {
      int e = csr[b + t];
      int sv = csrc[e];
      s = (sv >= 0) ? sv : 0;
      w = (sv >= 0) ? 1.f : 0.f;
    } else {
      s = 0;
      w = 0.f;
    }
  };

  int s0, s1, s2;
  float w0, w1, w2;
  fetchS(0, s0, w0);
  fetchS(1, s1, w1);
  fetchS(2, s2, w2);
  float4 h0 = *(const float4*)(H + (size_t)s0 * 200 + 4 * lane);
  float4 h1 = *(const float4*)(H + (size_t)s1 * 200 + 4 * lane);
  float4 acc = make_float4(0.f, 0.f, 0.f, 0.f);
  for (int t = 0; t < deg; t++) {
    int s3;
    float w3;
    fetchS(t + 3, s3, w3);
    float4 h2 = *(const float4*)(H + (size_t)s2 * 200 + 4 * lane);
    acc.x = __fadd_rn(acc.x, __fmul_rn(w0, h0.x));
    acc.y = __fadd_rn(acc.y, __fmul_rn(w0, h0.y));
    acc.z = __fadd_rn(acc.z, __fmul_rn(w0, h0.z));
    acc.w = __fadd_rn(acc.w, __fmul_rn(w0, h0.w));
    h0 = h1; h1 = h2;
    w0 = w1; w1 = w2; w2 = w3;
    s2 = s3;
  }
  *(float4*)(AGG + (size_t)node * 200 + 4 * lane) = acc;
}

// score[i] = tanh((agg_i . Wrel + h_i . Wroot) + b)
__global__ __launch_bounds__(256) void score2_k(
    const float* __restrict__ AGG, const float* __restrict__ H,
    const float* __restrict__ wrel, const float* __restrict__ wroot,
    const float* __restrict__ bp, float* __restrict__ score, int n) {
  int node = blockIdx.x * 4 + (threadIdx.x >> 6);
  int lane = threadIdx.x & 63;
  if (node >= n) return;
  const float* arow = AGG + (size_t)node * 200;
  const float* hrow = H + (size_t)node * 200;
  float s1 = 0.f, s2 = 0.f;
  for (int d = lane; d < 200; d += 64) {
    s1 += arow[d] * wrel[d];
    s2 += hrow[d] * wroot[d];
  }
  for (int off = 32; off; off >>= 1) {
    s1 += __shfl_down(s1, off);
    s2 += __shfl_down(s2, off);
  }
  if (lane == 0) score[node] = tanhf((s1 + s2) + bp[0]);
}

// ---------------- stable LSD radix sort -> exact lax.top_k rank --------------
// Stable ascending sort on ~enc (= descending score, ties by original index
// ascending): sorted position r IS rank[i] under
//   rank[i] = #{j : s_j > s_i || (s_j == s_i && j < i)}.
// Tie-proof: O(n) regardless of score distribution (tanh saturation safe).
// -0.0 canonicalized to +0.0 so float equality semantics are preserved.

// pass-0: encode key + write key/pay + histogram digit 0 (fused renc+rhist)
__global__ __launch_bounds__(256) void rhenc_k(const float* __restrict__ score,
                                               unsigned* __restrict__ keyA,
                                               int* __restrict__ payA,
                                               int* __restrict__ counts,
                                               int n, int NB) {
  __shared__ int hist[256];
  hist[threadIdx.x] = 0;
  __syncthreads();
  int i = blockIdx.x * 256 + threadIdx.x;
  if (i < n) {
    unsigned b = __float_as_uint(score[i]);
    if (b == 0x80000000u) b = 0u;  // -0 -> +0
    unsigned enc = (b & 0x80000000u) ? ~b : (b | 0x80000000u);
    unsigned key = ~enc;  // ascending sort of ~enc == descending score
    keyA[i] = key;
    payA[i] = i;
    atomicAdd(&hist[key & 255u], 1);
  }
  __syncthreads();
  counts[threadIdx.x * NB + blockIdx.x] = hist[threadIdx.x];
}

// counts[digit * NB + block] = #elements in block with this digit
__global__ __launch_bounds__(256) void rhist_k(const unsigned* __restrict__ key,
                                               int* __restrict__ counts,
                                               int n, int NB, int shift) {
  __shared__ int hist[256];
  hist[threadIdx.x] = 0;
  __syncthreads();
  int i = blockIdx.x * 256 + threadIdx.x;
  if (i < n) atomicAdd(&hist[(key[i] >> shift) & 255u], 1);
  __syncthreads();
  counts[threadIdx.x * NB + blockIdx.x] = hist[threadIdx.x];
}

// single block: exclusive scan of counts in digit-major, block-minor order
__global__ __launch_bounds__(256) void rscan_k(const int* __restrict__ counts,
                                               int* __restrict__ base, int NB) {
  __shared__ int tot[256];
  int t = threadIdx.x;
  int s = 0;
  for (int b = 0; b < NB; b++) s += counts[t * NB + b];
  tot[t] = s;
  __syncthreads();
  if (t == 0) {
    int run = 0;
    for (int i = 0; i < 256; i++) { int v = tot[i]; tot[i] = run; run += v; }
  }
  __syncthreads();
  int run = tot[t];
  for (int b = 0; b < NB; b++) { base[t * NB + b] = run; run += counts[t * NB + b]; }
}

// stable scatter: within-block offset = #earlier threads with same digit
// (no atomics -> deterministic & stable across any scheduling)
__global__ __launch_bounds__(256) void rscatter_k(
    const unsigned* __restrict__ keyIn, const int* __restrict__ payIn,
    const int* __restrict__ base, unsigned* __restrict__ keyOut,
    int* __restrict__ payOut, int n, int NB, int shift) {
  __shared__ int dig[256];
  int t = threadIdx.x;
  int i = blockIdx.x * 256 + t;
  unsigned k = 0u;
  int p = 0, d = -1;
  if (i < n) {
    k = keyIn[i];
    p = payIn[i];
    d = (int)((k >> shift) & 255u);
  }
  dig[t] = d;
  __syncthreads();
  if (i < n) {
    int local = 0;
    for (int j = 0; j < t; j++) local += (dig[j] == d) ? 1 : 0;
    int pos = base[d * NB + blockIdx.x] + local;
    keyOut[pos] = k;
    payOut[pos] = p;
  }
}

// final pass (shift=24): scatter position IS the rank -> write perm/inv/oout
// directly (fuses old ranksort_k + orig_update_k; skips key/pay writeback)
__global__ __launch_bounds__(256) void rscatterF_k(
    const unsigned* __restrict__ keyIn, const int* __restrict__ payIn,
    const int* __restrict__ base, const int* __restrict__ oin,
    int* __restrict__ oout, int* __restrict__ perm, int* __restrict__ inv,
    int n, int NB, int k) {
  __shared__ int dig[256];
  int t = threadIdx.x;
  int i = blockIdx.x * 256 + t;
  int p = 0, d = -1;
  if (i < n) {
    p = payIn[i];
    d = (int)((keyIn[i] >> 24) & 255u);
  }
  dig[t] = d;
  __syncthreads();
  if (i < n) {
    int local = 0;
    for (int j = 0; j < t; j++) local += (dig[j] == d) ? 1 : 0;
    int pos = base[d * NB + blockIdx.x] + local;  // final stable-sort rank
    if (pos < k) { perm[pos] = p; inv[p] = pos; oout[pos] = oin[p]; }
    else inv[p] = -1;
  }
}

__global__ __launch_bounds__(256) void gather_k(
    const float* __restrict__ H, const int* __restrict__ perm,
    const float* __restrict__ score, float* __restrict__ Ho, int k) {
  int r = blockIdx.x;
  int d = threadIdx.x;
  int p = perm[r];
  float s = score[p];
  if (d < 200) Ho[(size_t)r * 200 + d] = __fmul_rn(H[(size_t)p * 200 + d], s);
}

__global__ __launch_bounds__(256) void remap_k(int* __restrict__ cs,
                                               int* __restrict__ cd,
                                               const int* __restrict__ inv, int E) {
  int e = blockIdx.x * 256 + threadIdx.x;
  if (e >= E) return;
  int a = cs[e];
  if (a < 0) return;  // already invalid, stays invalid
  int na = inv[a], nb = inv[cd[e]];
  bool valid = (na >= 0) && (nb >= 0);
  cs[e] = valid ? na : -1;
  cd[e] = valid ? nb : -1;
}

__global__ __launch_bounds__(256) void out_copy_k(const float* __restrict__ h,
                                                  float* __restrict__ out, int cnt) {
  int t = blockIdx.x * 256 + threadIdx.x;
  if (t < cnt) out[t] = h[t];
}

// ---------------------------------------------------------------------------
extern "C" void kernel_launch(void* const* d_in, const int* in_sizes, int n_in,
                              void* d_out, int out_size, void* d_ws, size_t ws_size,
                              hipStream_t stream) {
  const int ID = 128, HD = 200;
  const int N = in_sizes[0] / ID;   // 50000
  const int E = in_sizes[1];        // 800000
  const int ET = E + N;
  const int total = N * HD;         // 10,000,000

  const float* x = (const float*)d_in[0];
  const int* src = (const int*)d_in[1];
  const int* dst = (const int*)d_in[2];
  const float* W[3]   = {(const float*)d_in[3], (const float*)d_in[7], (const float*)d_in[11]};
  const float* asv[3] = {(const float*)d_in[4], (const float*)d_in[8], (const float*)d_in[12]};
  const float* adv[3] = {(const float*)d_in[5], (const float*)d_in[9], (const float*)d_in[13]};
  const float* bv[3]  = {(const float*)d_in[6], (const float*)d_in[10], (const float*)d_in[14]};
  const float* Wrel  = (const float*)d_in[15];
  const float* Wroot = (const float*)d_in[16];
  const float* bpool = (const float*)d_in[17];

  char* ws = (char*)d_ws;
  float*    bufA  = (float*)(ws + 0);           // 40,000,000
  float*    bufB  = (float*)(ws + 40000000);    // 40,000,000
  float*    as_   = (float*)(ws + 80000000);    //   200,000
  float*    ad_   = (float*)(ws + 80200000);    //   200,000
  float*    ee_   = (float*)(ws + 80400000);    // 3,400,000
  unsigned* menc  = (unsigned*)(ws + 83800000); //   200,000
  float*    den   = (float*)(ws + 84000000);    //   200,000
  float*    score = (float*)(ws + 84200000);    //   200,000
  int*      rank_ = (int*)(ws + 84400000);      //   200,000 (CSR count scratch)
  int*      perm_ = (int*)(ws + 84600000);      //   200,000
  int*      inv_  = (int*)(ws + 84800000);      //   200,000
  int*      origA = (int*)(ws + 85000000);      //   200,000
  int*      origB = (int*)(ws + 85200000);      //   200,000
  int*      rowptr= (int*)(ws + 85400000);      //   250,000 (N+1 ints)
  int*      curs  = (int*)(ws + 85650000);      //   200,000
  int*      csr   = (int*)(ws + 85850000);      // 3,200,000
  int*      csrc  = (int*)(ws + 89050000);      // 3,200,000
  int*      cdst  = (int*)(ws + 92250000);      // 3,200,000  -> total 95.45 MB

  // Radix scratch reuses the GAT-only ee_ region (free during pooling):
  // six 256 KiB slots: keyA keyB payA payB counts base (NB<=196 -> 200,704 B)
  char* rx = ws + 80400000;
  unsigned* keyA   = (unsigned*)(rx + 0 * 262144);
  unsigned* keyB   = (unsigned*)(rx + 1 * 262144);
  int*      payA   = (int*)(rx + 2 * 262144);
  int*      payB   = (int*)(rx + 3 * 262144);
  int*      rcounts= (int*)(rx + 4 * 262144);
  int*      rbase  = (int*)(rx + 5 * 262144);

  // Host-side fold_in(key(42), i) = threefry2x32(k=(0,42), x=(0,i)).
  uint32_t fk0[3], fk1[3];
  for (int i = 0; i < 3; i++) {
    uint32_t a = 0u, b = (uint32_t)i;
    threefry2x32(0u, 42u, a, b);
    fk0[i] = a; fk1[i] = b;
  }

  const int B256 = 256;
  // ---------------- CSR build (once) ----------------
  hipMemsetAsync(rank_, 0, (size_t)N * 4, stream);
  indeg_k<<<(E + 255) / 256, B256, 0, stream>>>(dst, rank_, E);
  scan_k<<<1, B256, 0, stream>>>(rank_, rowptr, N);
  cpyint_k<<<(N + 255) / 256, B256, 0, stream>>>(rowptr, curs, N);
  place_k<<<(E + 255) / 256, B256, 0, stream>>>(dst, curs, csr, E);
  sortrow_k<<<(N + 255) / 256, B256, 0, stream>>>(rowptr, csr, N);

  // ---------------- 3 GAT layers ----------------
  for (int i = 0; i < 3; i++) {
    const float* in = (i == 0) ? x : bufB;
    int K = (i == 0) ? ID : HD;
    gemm200_k<<<(N + 127) / 128, B256, 0, stream>>>(in, W[i], bufA, N, K);
    dual_dot_k<<<(N + 3) / 4, B256, 0, stream>>>(bufA, asv[i], adv[i], as_, ad_, N);
    hipMemsetAsync(menc, 0, (size_t)N * 4, stream);
    edge_max_k<<<(ET + 255) / 256, B256, 0, stream>>>(src, dst, as_, ad_, menc, E, N);
    ee_k<<<(ET + 255) / 256, B256, 0, stream>>>(src, dst, as_, ad_, menc, ee_, E, N);
    den_k<<<(N + 255) / 256, B256, 0, stream>>>(rowptr, csr, ee_, den, E, N);
    alpha_k<<<(ET + 255) / 256, B256, 0, stream>>>(dst, den, ee_, E, N);
    gat_out_k<<<(N + 3) / 4, B256, 0, stream>>>(rowptr, csr, src, ee_, bufA, bufB, E, N);
    epi_k<<<(total + 255) / 256, B256, 0, stream>>>(bufB, bv[i], fk0[i], fk1[i], total);
  }

  // ---------------- SAGPooling loop ----------------
  einit_k<<<(E + 255) / 256, B256, 0, stream>>>(src, dst, csrc, cdst, origA, E, N);
  float* hcur = bufB;
  float* hnext = bufA;   // also serves as AGG scratch each round
  int* ocur = origA;
  int* onext = origB;
  int n = N;
  while (true) {
    int k = (n + 1) / 2;  // ceil(0.5 n)
    int NB = (n + 255) / 256;
    pool_agg_k<<<(n + 3) / 4, B256, 0, stream>>>(rowptr, csr, csrc, ocur, hcur, hnext, n);
    score2_k<<<(n + 3) / 4, B256, 0, stream>>>(hnext, hcur, Wrel, Wroot, bpool, score, n);
    // exact rank via stable 4x8-bit LSD radix sort (tie-proof, O(n))
    rhenc_k<<<NB, B256, 0, stream>>>(score, keyA, payA, rcounts, n, NB);
    rscan_k<<<1, B256, 0, stream>>>(rcounts, rbase, NB);
    rscatter_k<<<NB, B256, 0, stream>>>(keyA, payA, rbase, keyB, payB, n, NB, 0);
    rhist_k<<<NB, B256, 0, stream>>>(keyB, rcounts, n, NB, 8);
    rscan_k<<<1, B256, 0, stream>>>(rcounts, rbase, NB);
    rscatter_k<<<NB, B256, 0, stream>>>(keyB, payB, rbase, keyA, payA, n, NB, 8);
    rhist_k<<<NB, B256, 0, stream>>>(keyA, rcounts, n, NB, 16);
    rscan_k<<<1, B256, 0, stream>>>(rcounts, rbase, NB);
    rscatter_k<<<NB, B256, 0, stream>>>(keyA, payA, rbase, keyB, payB, n, NB, 16);
    rhist_k<<<NB, B256, 0, stream>>>(keyB, rcounts, n, NB, 24);
    rscan_k<<<1, B256, 0, stream>>>(rcounts, rbase, NB);
    rscatterF_k<<<NB, B256, 0, stream>>>(keyB, payB, rbase, ocur, onext, perm_, inv_,
                                         n, NB, k);
    gather_k<<<k, B256, 0, stream>>>(hcur, perm_, score, hnext, k);
    remap_k<<<(E + 255) / 256, B256, 0, stream>>>(csrc, cdst, inv_, E);
    { float* t = hcur; hcur = hnext; hnext = t; }
    { int* t = ocur; ocur = onext; onext = t; }
    n = k;
    if (n <= 512) break;
  }

  // ---------------- output: zeros(512,200) with first n rows = h -------------
  hipMemsetAsync(d_out, 0, (size_t)out_size * 4, stream);
  out_copy_k<<<(n * HD + 255) / 256, B256, 0, stream>>>(hcur, (float*)d_out, n * HD);
}